// Round 7
// baseline (568.291 us; speedup 1.0000x reference)
//
#include <hip/hip_runtime.h>
#include <math.h>

#define HH 96
#define WW 96
#define HW 9216
#define CIN 192
#define CMID 180
#define NB 2
#define NG 10
#define KTAPS 9
#define KP 1760         // padded K: 10 groups x 176; per group: 3 trips {56,56,64}, tap-major
#define GCH 176
#define MP 192          // padded M for dcn GEMM

typedef __attribute__((ext_vector_type(8))) short short8;
typedef __attribute__((ext_vector_type(4))) float f32x4;
union FragU { uint2 u2[2]; short8 v; };

static __device__ inline unsigned short f2bf(float f) {
    unsigned x = __float_as_uint(f);
    unsigned r = (x + 0x7fffu + ((x >> 16) & 1u)) >> 16;   // RNE
    return (unsigned short)r;
}

// ---------------- generic tiled fp32 GEMM (reduce / offset / expand) ----------------
template<bool COMBINE>
__global__ __launch_bounds__(256)
void gemm_k(const float* __restrict__ A,
            const float* __restrict__ B0, const float* __restrict__ B1,
            const float* __restrict__ attnb,
            const float* __restrict__ bias, float* __restrict__ C,
            int M, int N, int K, int ldb, int ldc, int bsB, int bsC)
{
    const int b = blockIdx.z;
    const float* Bp0 = B0 + (size_t)b * bsB;
    const float* Bp1 = COMBINE ? (B1 + (size_t)b * bsB) : nullptr;
    float* Cp = C + (size_t)b * bsC;
    float a0 = 0.f, a1 = 0.f;
    if (COMBINE) { a0 = attnb[2*b]; a1 = attnb[2*b+1]; }

    __shared__ float As[16][68];
    __shared__ float Bs[16][64];

    const int tid = threadIdx.x;
    const int m0 = blockIdx.x * 64, n0 = blockIdx.y * 64;
    const int am = tid >> 2, ak = (tid & 3) << 2;
    const int bk = tid >> 4, bn = (tid & 15) << 2;
    const int ty = tid >> 4, tx = tid & 15;

    float acc[4][4] = {};

    for (int k0 = 0; k0 < K; k0 += 16) {
        float4 av = make_float4(0.f, 0.f, 0.f, 0.f);
        if ((m0 + am) < M && (k0 + ak) < K)
            av = *reinterpret_cast<const float4*>(A + (size_t)(m0 + am) * K + k0 + ak);
        As[ak + 0][am] = av.x; As[ak + 1][am] = av.y;
        As[ak + 2][am] = av.z; As[ak + 3][am] = av.w;

        float4 bv = make_float4(0.f, 0.f, 0.f, 0.f);
        if ((k0 + bk) < K) {
            size_t o = (size_t)(k0 + bk) * ldb + n0 + bn;
            bv = *reinterpret_cast<const float4*>(Bp0 + o);
            if (COMBINE) {
                float4 c4 = *reinterpret_cast<const float4*>(Bp1 + o);
                bv.x = a0 * bv.x + a1 * c4.x; bv.y = a0 * bv.y + a1 * c4.y;
                bv.z = a0 * bv.z + a1 * c4.z; bv.w = a0 * bv.w + a1 * c4.w;
            }
        }
        *reinterpret_cast<float4*>(&Bs[bk][bn]) = bv;
        __syncthreads();

        #pragma unroll
        for (int kk = 0; kk < 16; ++kk) {
            float4 a  = *reinterpret_cast<const float4*>(&As[kk][ty << 2]);
            float4 bb = *reinterpret_cast<const float4*>(&Bs[kk][tx << 2]);
            acc[0][0] += a.x * bb.x; acc[0][1] += a.x * bb.y; acc[0][2] += a.x * bb.z; acc[0][3] += a.x * bb.w;
            acc[1][0] += a.y * bb.x; acc[1][1] += a.y * bb.y; acc[1][2] += a.y * bb.z; acc[1][3] += a.y * bb.w;
            acc[2][0] += a.z * bb.x; acc[2][1] += a.z * bb.y; acc[2][2] += a.z * bb.z; acc[2][3] += a.z * bb.w;
            acc[3][0] += a.w * bb.x; acc[3][1] += a.w * bb.y; acc[3][2] += a.w * bb.z; acc[3][3] += a.w * bb.w;
        }
        __syncthreads();
    }

    #pragma unroll
    for (int i = 0; i < 4; ++i) {
        int m = m0 + (ty << 2) + i;
        if (m < M) {
            float bi = bias[m];
            #pragma unroll
            for (int j = 0; j < 4; ++j)
                Cp[(size_t)m * ldc + n0 + (tx << 2) + j] = acc[i][j] + bi;
        }
    }
}

// ---------------- weight convert to trip/tap-major padded bf16 [2][192][KP] ----------------
// per group (176): kr = trip*56 + r ; buckets {56,56,64}; r<54: tap=trip*3+r/18, c=r%18
__global__ __launch_bounds__(256)
void convw4_k(const float* __restrict__ w0, const float* __restrict__ w1,
              unsigned short* __restrict__ wbf)
{
    int idx = blockIdx.x * 256 + threadIdx.x;      // 2*192*1760 = 675840
    int set = idx / (MP * KP);
    int r0 = idx - set * MP * KP;
    int o = r0 / KP, k = r0 - o * KP;
    int g = k / GCH, kr = k - g * GCH;
    int trip = kr / 56; if (trip > 2) trip = 2;
    int r = kr - trip * 56;
    float v = 0.f;
    if (o < CMID && r < 54) {
        int tap = trip * 3 + r / 18, c = r % 18;
        v = (set ? w1 : w0)[((size_t)o * CMID + g * 18 + c) * KTAPS + tap];
    }
    wbf[idx] = f2bf(v);
}

// ---------------- deformable im2col gather -> bf16 patch [b][pix][KP] ----------------
// Thread = (pixel, group, trip-of-3-taps). Wave-coherent: 64 lanes = 64 adjacent
// pixels on the SAME channel plane. 3x threads + ~75 VGPR vs R6's (px,g) mapping
// -> 3-6x more loads in flight to hide L2 latency. Math bit-identical to R6.
__global__ __launch_bounds__(256)
void gather4_k(const float* __restrict__ xr, const float* __restrict__ offs,
               unsigned short* __restrict__ patch, int set, int p0, int nchunk)
{
    const int b = blockIdx.z / 3, trip = blockIdx.z % 3;
    const int g = blockIdx.y;                        // 0..9
    const int pl = blockIdx.x * 256 + threadIdx.x;   // pixel within chunk
    const int pix = p0 + pl;
    const int h = pix / WW, w = pix % WW;

    const float* ob = offs + (((size_t)b * 2 + set) * CMID + g * 18) * HW + pix;

    int i00A[3], i01A[3], i10A[3], i11A[3];
    float w00A[3], w01A[3], w10A[3], w11A[3];
    #pragma unroll
    for (int tl = 0; tl < 3; ++tl) {
        const int tap = trip * 3 + tl;
        float oy = ob[(size_t)(2 * tap) * HW];
        float ox = ob[(size_t)(2 * tap + 1) * HW];
        float sy = oy + (float)(tap / 3 - 1 + h);
        float sx = ox + (float)(tap % 3 - 1 + w);
        float yf = floorf(sy), xf = floorf(sx);
        float dy = sy - yf, dx = sx - xf;
        int y0 = (int)yf, x0 = (int)xf;
        bool vy0 = (unsigned)y0 < (unsigned)HH, vy1 = (unsigned)(y0 + 1) < (unsigned)HH;
        bool vx0 = (unsigned)x0 < (unsigned)WW, vx1 = (unsigned)(x0 + 1) < (unsigned)WW;
        int yc0 = min(max(y0, 0), HH - 1), yc1 = min(max(y0 + 1, 0), HH - 1);
        int xc0 = min(max(x0, 0), WW - 1), xc1 = min(max(x0 + 1, 0), WW - 1);
        i00A[tl] = yc0 * WW + xc0; i01A[tl] = yc0 * WW + xc1;
        i10A[tl] = yc1 * WW + xc0; i11A[tl] = yc1 * WW + xc1;
        w00A[tl] = (1.f - dy) * (1.f - dx) * ((vy0 && vx0) ? 1.f : 0.f);
        w01A[tl] = (1.f - dy) * dx         * ((vy0 && vx1) ? 1.f : 0.f);
        w10A[tl] = dy * (1.f - dx)         * ((vy1 && vx0) ? 1.f : 0.f);
        w11A[tl] = dy * dx                 * ((vy1 && vx1) ? 1.f : 0.f);
    }

    const int ndw = (trip == 2) ? 32 : 28;           // dwords incl zero pad
    unsigned u[32];
    #pragma unroll
    for (int i = 0; i < 32; ++i) u[i] = 0u;

    const float* xb = xr + ((size_t)b * CMID + g * 18) * HW;
    #pragma unroll
    for (int c = 0; c < 18; ++c) {
        const float* xc = xb + (size_t)c * HW;
        #pragma unroll
        for (int tl = 0; tl < 3; ++tl) {
            float v = w00A[tl] * xc[i00A[tl]] + w01A[tl] * xc[i01A[tl]]
                    + w10A[tl] * xc[i10A[tl]] + w11A[tl] * xc[i11A[tl]];
            int e = tl * 18 + c;                     // kr within trip
            unsigned hh = (unsigned)f2bf(v);
            if (e & 1) u[e >> 1] |= hh << 16; else u[e >> 1] |= hh;
        }
    }

    uint4* dst = (uint4*)(patch + ((size_t)(b * nchunk) + pl) * KP + g * GCH + trip * 56);
    if (trip == 2) {
        #pragma unroll
        for (int i = 0; i < 8; ++i)
            dst[i] = make_uint4(u[4*i], u[4*i+1], u[4*i+2], u[4*i+3]);
    } else {
        #pragma unroll
        for (int i = 0; i < 7; ++i)
            dst[i] = make_uint4(u[4*i], u[4*i+1], u[4*i+2], u[4*i+3]);
    }
    (void)ndw;
}

// ---------------- MFMA bf16 dcn GEMM: C[180,n] += A[192,KP] * patch^T ----------------
// block: 256 thr (4 waves), tile BM=192 x BN=64, K-step 32, reg double-buffer
__global__ __launch_bounds__(256)
void dgemm_k(const unsigned short* __restrict__ A, const unsigned short* __restrict__ patch,
             const float* __restrict__ bias, float* __restrict__ C, int nchunk, int p0)
{
    __shared__ uint4 smem[1024];                 // 12KB A-tile + 4KB B-tile
    char* lds = (char*)smem;
    const int b = blockIdx.z, n0 = blockIdx.x * 64;
    const int tid = threadIdx.x;
    const int wv = tid >> 6, l = tid & 63;
    const int lg = l >> 4, lm = l & 15;
    const int arow = tid >> 2, aseg = tid & 3;

    const unsigned short* Ag = A + (size_t)arow * KP + aseg * 8;
    const unsigned short* Bg = patch + ((size_t)(b * nchunk + n0 + arow)) * KP + aseg * 8;

    // swizzled LDS write offsets: mask(row) = ((row&3)<<4)|((row&4)<<1)
    int wbA[3], wmA[3];
    #pragma unroll
    for (int i = 0; i < 3; ++i) {
        int row = arow + (i << 6);
        wbA[i] = row << 6;
        wmA[i] = (aseg << 4) ^ (((row & 3) << 4) | ((row & 4) << 1));
    }
    const int wbB = 12288 + (arow << 6);
    const int wmB = (aseg << 4) ^ (((arow & 3) << 4) | ((arow & 4) << 1));

    // swizzled LDS read offsets for fragments
    int aoff[3][2], boff[4][2];
    #pragma unroll
    for (int fr = 0; fr < 3; ++fr) {
        int row = wv * 48 + fr * 16 + lm;
        int m = ((row & 3) << 4) | ((row & 4) << 1);
        aoff[fr][0] = (row << 6) + (((lg << 3)     ) ^ m);
        aoff[fr][1] = (row << 6) + (((lg << 3) + 32) ^ m);
    }
    #pragma unroll
    for (int nc = 0; nc < 4; ++nc) {
        int n = nc * 16 + lm;
        int m = ((n & 3) << 4) | ((n & 4) << 1);
        boff[nc][0] = 12288 + (n << 6) + (((lg << 3)     ) ^ m);
        boff[nc][1] = 12288 + (n << 6) + (((lg << 3) + 32) ^ m);
    }

    uint4 ra0 = *(const uint4*)(Ag);
    uint4 ra1 = *(const uint4*)(Ag + (size_t)64 * KP);
    uint4 ra2 = *(const uint4*)(Ag + (size_t)128 * KP);
    uint4 rb  = *(const uint4*)(Bg);

    f32x4 acc[3][4];
    #pragma unroll
    for (int i = 0; i < 3; ++i)
        #pragma unroll
        for (int j = 0; j < 4; ++j)
            acc[i][j] = (f32x4){0.f, 0.f, 0.f, 0.f};

    for (int kt = 0; kt < KP / 32; ++kt) {
        __syncthreads();
        *(uint2*)(lds + wbA[0] + wmA[0])       = make_uint2(ra0.x, ra0.y);
        *(uint2*)(lds + wbA[0] + (wmA[0] ^ 8)) = make_uint2(ra0.z, ra0.w);
        *(uint2*)(lds + wbA[1] + wmA[1])       = make_uint2(ra1.x, ra1.y);
        *(uint2*)(lds + wbA[1] + (wmA[1] ^ 8)) = make_uint2(ra1.z, ra1.w);
        *(uint2*)(lds + wbA[2] + wmA[2])       = make_uint2(ra2.x, ra2.y);
        *(uint2*)(lds + wbA[2] + (wmA[2] ^ 8)) = make_uint2(ra2.z, ra2.w);
        *(uint2*)(lds + wbB + wmB)             = make_uint2(rb.x, rb.y);
        *(uint2*)(lds + wbB + (wmB ^ 8))       = make_uint2(rb.z, rb.w);
        __syncthreads();

        if (kt < KP / 32 - 1) {
            int k0 = (kt + 1) * 32;
            ra0 = *(const uint4*)(Ag + k0);
            ra1 = *(const uint4*)(Ag + (size_t)64 * KP + k0);
            ra2 = *(const uint4*)(Ag + (size_t)128 * KP + k0);
            rb  = *(const uint4*)(Bg + k0);
        }

        FragU af[3], bf[4];
        #pragma unroll
        for (int fr = 0; fr < 3; ++fr) {
            af[fr].u2[0] = *(const uint2*)(lds + aoff[fr][0]);
            af[fr].u2[1] = *(const uint2*)(lds + aoff[fr][1]);
        }
        #pragma unroll
        for (int nc = 0; nc < 4; ++nc) {
            bf[nc].u2[0] = *(const uint2*)(lds + boff[nc][0]);
            bf[nc].u2[1] = *(const uint2*)(lds + boff[nc][1]);
        }
        #pragma unroll
        for (int fr = 0; fr < 3; ++fr)
            #pragma unroll
            for (int nc = 0; nc < 4; ++nc)
                acc[fr][nc] = __builtin_amdgcn_mfma_f32_16x16x32_bf16(
                    af[fr].v, bf[nc].v, acc[fr][nc], 0, 0, 0);
    }

    #pragma unroll
    for (int fr = 0; fr < 3; ++fr) {
        #pragma unroll
        for (int r = 0; r < 4; ++r) {
            int rr = wv * 48 + fr * 16 + lg * 4 + r;
            if (rr < CMID) {
                float bi = bias[rr];
                float* Cr = C + (size_t)b * CMID * HW + (size_t)rr * HW + p0 + n0 + lm;
                #pragma unroll
                for (int nc = 0; nc < 4; ++nc)
                    Cr[nc * 16] = acc[fr][nc][r] + bi;
            }
        }
    }
}

// ---------------- mean over HW of (f_w + f_h) ----------------
__global__ __launch_bounds__(256)
void avg_k(const float* __restrict__ fw, const float* __restrict__ fh,
           float* __restrict__ favg)
{
    const int bm = blockIdx.x;
    const size_t base = (size_t)bm * HW;
    float s = 0.f;
    for (int i = threadIdx.x; i < HW; i += 256)
        s += fw[base + i] + fh[base + i];
    #pragma unroll
    for (int off = 32; off > 0; off >>= 1) s += __shfl_down(s, off, 64);
    __shared__ float sb[4];
    const int tid = threadIdx.x;
    if ((tid & 63) == 0) sb[tid >> 6] = s;
    __syncthreads();
    if (tid == 0) favg[bm] = (sb[0] + sb[1] + sb[2] + sb[3]) / (float)HW;
}

// ---------------- attention softmax ----------------
__global__ __launch_bounds__(256)
void attn_k(const float* __restrict__ favg, const float* __restrict__ w_attn,
            const float* __restrict__ b_attn, float* __restrict__ attnb)
{
    const int b = blockIdx.x;
    const int t = threadIdx.x;
    float z0 = 0.f, z1 = 0.f;
    if (t < CMID) {
        float f = favg[b * CMID + t];
        z0 = w_attn[t] * f;
        z1 = w_attn[CMID + t] * f;
    }
    #pragma unroll
    for (int off = 32; off > 0; off >>= 1) {
        z0 += __shfl_down(z0, off, 64);
        z1 += __shfl_down(z1, off, 64);
    }
    __shared__ float s0[4], s1[4];
    if ((t & 63) == 0) { s0[t >> 6] = z0; s1[t >> 6] = z1; }
    __syncthreads();
    if (t == 0) {
        float a = s0[0] + s0[1] + s0[2] + s0[3] + b_attn[0];
        float c = s1[0] + s1[1] + s1[2] + s1[3] + b_attn[1];
        float m = fmaxf(a, c);
        float e0 = expf(a - m), e1 = expf(c - m);
        float inv = 1.f / (e0 + e1);
        attnb[2 * b + 0] = e0 * inv;   // multiplies f_h
        attnb[2 * b + 1] = e1 * inv;   // multiplies f_w
    }
}

extern "C" void kernel_launch(void* const* d_in, const int* in_sizes, int n_in,
                              void* d_out, int out_size, void* d_ws, size_t ws_size,
                              hipStream_t stream) {
    const float* x        = (const float*)d_in[0];
    const float* w_reduce = (const float*)d_in[1];
    const float* b_reduce = (const float*)d_in[2];
    const float* w_offset = (const float*)d_in[3];
    const float* b_offset = (const float*)d_in[4];
    const float* w_dcnw   = (const float*)d_in[5];
    const float* b_dcnw   = (const float*)d_in[6];
    const float* w_dcnh   = (const float*)d_in[7];
    const float* b_dcnh   = (const float*)d_in[8];
    const float* w_expand = (const float*)d_in[9];
    const float* b_expand = (const float*)d_in[10];
    const float* w_attn   = (const float*)d_in[11];
    const float* b_attn   = (const float*)d_in[12];
    float* out = (float*)d_out;

    // workspace layout
    char* base = (char*)d_ws;
    size_t o = 0;
    float* xr    = (float*)(base + o); o += (size_t)NB * CMID * HW * 4;
    float* offs  = (float*)(base + o); o += (size_t)NB * 2 * CMID * HW * 4;
    float* fw    = (float*)(base + o); o += (size_t)NB * CMID * HW * 4;
    float* fh    = (float*)(base + o); o += (size_t)NB * CMID * HW * 4;
    float* favg  = (float*)(base + o); o += (size_t)NB * CMID * 4;
    float* attnb = (float*)(base + o); o += 32;
    unsigned short* wbf = (unsigned short*)(base + o); o += (size_t)2 * MP * KP * 2;
    unsigned short* patch = (unsigned short*)(base + o);

    int nchunk = 2304;
    const int cand[3] = {9216, 4608, 2304};        // all divisible by 256
    for (int i = 0; i < 3; ++i) {
        size_t need = o + (size_t)NB * cand[i] * KP * 2;
        if (need <= ws_size) { nchunk = cand[i]; break; }
    }

    // 0) convert dcn weights to trip/tap-major padded bf16 layout
    convw4_k<<<dim3((2 * MP * KP) / 256), 256, 0, stream>>>(w_dcnw, w_dcnh, wbf);

    // 1) xr = w_reduce @ x + b_reduce
    gemm_k<false><<<dim3(3, HW / 64, NB), 256, 0, stream>>>(
        w_reduce, x, nullptr, nullptr, b_reduce, xr,
        CMID, HW, CIN, HW, HW, CIN * HW, CMID * HW);

    // 2) offs = w_offset @ xr + b_offset
    gemm_k<false><<<dim3(6, HW / 64, NB), 256, 0, stream>>>(
        w_offset, xr, nullptr, nullptr, b_offset, offs,
        2 * CMID, HW, CMID, HW, HW, CMID * HW, 2 * CMID * HW);

    // 3) deformable convs via bf16 MFMA: set0 -> f_w (w_dcnw), set1 -> f_h (w_dcnh)
    for (int set = 0; set < 2; ++set) {
        const float* bD = set ? b_dcnh : b_dcnw;
        float* fD = set ? fh : fw;
        for (int p0 = 0; p0 < HW; p0 += nchunk) {
            gather4_k<<<dim3(nchunk / 256, NG, 3 * NB), 256, 0, stream>>>(
                xr, offs, patch, set, p0, nchunk);
            dgemm_k<<<dim3(nchunk / 64, 1, NB), 256, 0, stream>>>(
                wbf + (size_t)set * MP * KP, patch, bD, fD, nchunk, p0);
        }
    }

    // 4) f_avg = mean_HW(f_w + f_h)
    avg_k<<<dim3(NB * CMID), 256, 0, stream>>>(fw, fh, favg);

    // 5) attn = softmax(w_attn @ f_avg + b_attn)
    attn_k<<<dim3(NB), 256, 0, stream>>>(favg, w_attn, b_attn, attnb);

    // 6) out = w_expand @ (a0*f_h + a1*f_w) + b_expand
    gemm_k<true><<<dim3(3, HW / 64, NB), 256, 0, stream>>>(
        w_expand, fh, fw, attnb, b_expand, out,
        CIN, HW, CMID, HW, HW, CMID * HW, CIN * HW);
}

// Round 9
// 446.505 us; speedup vs baseline: 1.2728x; 1.2728x over previous
//
#include <hip/hip_runtime.h>
#include <math.h>

#define HH 96
#define WW 96
#define HW 9216
#define CIN 192
#define CMID 180
#define NB 2
#define NG 10
#define KTAPS 9
#define KP 1760         // padded K: 10 groups x 176; per group tap-major: kr = kk*18 + c, 162 real
#define GCH 176
#define MP 192          // padded M for dcn GEMM
#define CP 20           // padded channel-last row (18 floats + 2 pad) = 80 B

typedef __attribute__((ext_vector_type(8))) short short8;
typedef __attribute__((ext_vector_type(4))) float f32x4;
union FragU { uint2 u2[2]; short8 v; };

static __device__ inline unsigned short f2bf(float f) {
    unsigned x = __float_as_uint(f);
    unsigned r = (x + 0x7fffu + ((x >> 16) & 1u)) >> 16;   // RNE
    return (unsigned short)r;
}

// ---------------- generic tiled fp32 GEMM (reduce / offset / expand) ----------------
// XT: also scatter C into channel-last xrt[b][g][n][CP] (reduce conv only)
template<bool COMBINE, bool XT>
__global__ __launch_bounds__(256)
void gemm_k(const float* __restrict__ A,
            const float* __restrict__ B0, const float* __restrict__ B1,
            const float* __restrict__ attnb,
            const float* __restrict__ bias, float* __restrict__ C,
            float* __restrict__ xrt,
            int M, int N, int K, int ldb, int ldc, int bsB, int bsC)
{
    const int b = blockIdx.z;
    const float* Bp0 = B0 + (size_t)b * bsB;
    const float* Bp1 = COMBINE ? (B1 + (size_t)b * bsB) : nullptr;
    float* Cp = C + (size_t)b * bsC;
    float a0 = 0.f, a1 = 0.f;
    if (COMBINE) { a0 = attnb[2*b]; a1 = attnb[2*b+1]; }

    __shared__ float As[16][68];
    __shared__ float Bs[16][64];

    const int tid = threadIdx.x;
    const int m0 = blockIdx.x * 64, n0 = blockIdx.y * 64;
    const int am = tid >> 2, ak = (tid & 3) << 2;
    const int bk = tid >> 4, bn = (tid & 15) << 2;
    const int ty = tid >> 4, tx = tid & 15;

    float acc[4][4] = {};

    for (int k0 = 0; k0 < K; k0 += 16) {
        float4 av = make_float4(0.f, 0.f, 0.f, 0.f);
        if ((m0 + am) < M && (k0 + ak) < K)
            av = *reinterpret_cast<const float4*>(A + (size_t)(m0 + am) * K + k0 + ak);
        As[ak + 0][am] = av.x; As[ak + 1][am] = av.y;
        As[ak + 2][am] = av.z; As[ak + 3][am] = av.w;

        float4 bv = make_float4(0.f, 0.f, 0.f, 0.f);
        if ((k0 + bk) < K) {
            size_t o = (size_t)(k0 + bk) * ldb + n0 + bn;
            bv = *reinterpret_cast<const float4*>(Bp0 + o);
            if (COMBINE) {
                float4 c4 = *reinterpret_cast<const float4*>(Bp1 + o);
                bv.x = a0 * bv.x + a1 * c4.x; bv.y = a0 * bv.y + a1 * c4.y;
                bv.z = a0 * bv.z + a1 * c4.z; bv.w = a0 * bv.w + a1 * c4.w;
            }
        }
        *reinterpret_cast<float4*>(&Bs[bk][bn]) = bv;
        __syncthreads();

        #pragma unroll
        for (int kk = 0; kk < 16; ++kk) {
            float4 a  = *reinterpret_cast<const float4*>(&As[kk][ty << 2]);
            float4 bb = *reinterpret_cast<const float4*>(&Bs[kk][tx << 2]);
            acc[0][0] += a.x * bb.x; acc[0][1] += a.x * bb.y; acc[0][2] += a.x * bb.z; acc[0][3] += a.x * bb.w;
            acc[1][0] += a.y * bb.x; acc[1][1] += a.y * bb.y; acc[1][2] += a.y * bb.z; acc[1][3] += a.y * bb.w;
            acc[2][0] += a.z * bb.x; acc[2][1] += a.z * bb.y; acc[2][2] += a.z * bb.z; acc[2][3] += a.z * bb.w;
            acc[3][0] += a.w * bb.x; acc[3][1] += a.w * bb.y; acc[3][2] += a.w * bb.z; acc[3][3] += a.w * bb.w;
        }
        __syncthreads();
    }

    #pragma unroll
    for (int i = 0; i < 4; ++i) {
        int m = m0 + (ty << 2) + i;
        if (m < M) {
            float bi = bias[m];
            #pragma unroll
            for (int j = 0; j < 4; ++j) {
                float s = acc[i][j] + bi;
                int n = n0 + (tx << 2) + j;
                Cp[(size_t)m * ldc + n] = s;
                if (XT)
                    xrt[((size_t)(b * NG + m / 18) * HW + n) * CP + (m % 18)] = s;
            }
        }
    }
}

// ---------------- weight convert to tap-major padded bf16 [2][192][KP] ----------------
// per group (176): kr = kk*18 + c for kr<162 ; 162..175 pad zero
__global__ __launch_bounds__(256)
void convw5_k(const float* __restrict__ w0, const float* __restrict__ w1,
              unsigned short* __restrict__ wbf)
{
    int idx = blockIdx.x * 256 + threadIdx.x;      // 2*192*1760 = 675840
    int set = idx / (MP * KP);
    int r0 = idx - set * MP * KP;
    int o = r0 / KP, k = r0 - o * KP;
    int g = k / GCH, kr = k - g * GCH;
    float v = 0.f;
    if (o < CMID && kr < 162) {
        int kk = kr / 18, c = kr % 18;
        v = (set ? w1 : w0)[((size_t)o * CMID + g * 18 + c) * KTAPS + kk];
    }
    wbf[idx] = f2bf(v);
}

// ---------------- deformable im2col gather, channel-last source ----------------
// Thread = (pixel, group). Per tap: 4 corners x 18ch read as 4xfloat4+float2 from
// xrt rows (<=2 cache lines each) -> 180 vector loads vs 648 scalar (gather3).
// One thread writes the full 352B patch row (aligned uint4 stores). Math bit-identical.
__global__ __launch_bounds__(256)
void gather5_k(const float* __restrict__ xrt, const float* __restrict__ offs,
               unsigned short* __restrict__ patch, int set, int p0, int nchunk)
{
    const int b = blockIdx.z;
    const int g = blockIdx.y;                        // 0..9
    const int pl = blockIdx.x * 256 + threadIdx.x;   // pixel within chunk
    const int pix = p0 + pl;
    const int h = pix / WW, w = pix % WW;

    const float* ob = offs + (((size_t)b * 2 + set) * CMID + g * 18) * HW + pix;
    float oyA[9], oxA[9];
    #pragma unroll
    for (int kk = 0; kk < 9; ++kk) {
        oyA[kk] = ob[(size_t)(2 * kk) * HW];
        oxA[kk] = ob[(size_t)(2 * kk + 1) * HW];
    }

    const float* gbase = xrt + (size_t)(b * NG + g) * HW * CP;
    unsigned u[88];
    #pragma unroll
    for (int i = 81; i < 88; ++i) u[i] = 0u;         // pad elems 162..175

    #pragma unroll
    for (int kk = 0; kk < 9; ++kk) {
        float sy = oyA[kk] + (float)(kk / 3 - 1 + h);
        float sx = oxA[kk] + (float)(kk % 3 - 1 + w);
        float yf = floorf(sy), xf = floorf(sx);
        float dy = sy - yf, dx = sx - xf;
        int y0 = (int)yf, x0 = (int)xf;
        bool vy0 = (unsigned)y0 < (unsigned)HH, vy1 = (unsigned)(y0 + 1) < (unsigned)HH;
        bool vx0 = (unsigned)x0 < (unsigned)WW, vx1 = (unsigned)(x0 + 1) < (unsigned)WW;
        int yc0 = min(max(y0, 0), HH - 1), yc1 = min(max(y0 + 1, 0), HH - 1);
        int xc0 = min(max(x0, 0), WW - 1), xc1 = min(max(x0 + 1, 0), WW - 1);
        float w00 = (1.f - dy) * (1.f - dx) * ((vy0 && vx0) ? 1.f : 0.f);
        float w01 = (1.f - dy) * dx         * ((vy0 && vx1) ? 1.f : 0.f);
        float w10 = dy * (1.f - dx)         * ((vy1 && vx0) ? 1.f : 0.f);
        float w11 = dy * dx                 * ((vy1 && vx1) ? 1.f : 0.f);

        const float* r00 = gbase + (size_t)(yc0 * WW + xc0) * CP;
        const float* r01 = gbase + (size_t)(yc0 * WW + xc1) * CP;
        const float* r10 = gbase + (size_t)(yc1 * WW + xc0) * CP;
        const float* r11 = gbase + (size_t)(yc1 * WW + xc1) * CP;

        float A00[18], A01[18], A10[18], A11[18];
        #pragma unroll
        for (int q = 0; q < 4; ++q) {
            *reinterpret_cast<float4*>(&A00[q * 4]) = *reinterpret_cast<const float4*>(r00 + q * 4);
            *reinterpret_cast<float4*>(&A01[q * 4]) = *reinterpret_cast<const float4*>(r01 + q * 4);
            *reinterpret_cast<float4*>(&A10[q * 4]) = *reinterpret_cast<const float4*>(r10 + q * 4);
            *reinterpret_cast<float4*>(&A11[q * 4]) = *reinterpret_cast<const float4*>(r11 + q * 4);
        }
        *reinterpret_cast<float2*>(&A00[16]) = *reinterpret_cast<const float2*>(r00 + 16);
        *reinterpret_cast<float2*>(&A01[16]) = *reinterpret_cast<const float2*>(r01 + 16);
        *reinterpret_cast<float2*>(&A10[16]) = *reinterpret_cast<const float2*>(r10 + 16);
        *reinterpret_cast<float2*>(&A11[16]) = *reinterpret_cast<const float2*>(r11 + 16);

        #pragma unroll
        for (int c = 0; c < 18; c += 2) {
            float v0 = w00 * A00[c]     + w01 * A01[c]     + w10 * A10[c]     + w11 * A11[c];
            float v1 = w00 * A00[c + 1] + w01 * A01[c + 1] + w10 * A10[c + 1] + w11 * A11[c + 1];
            u[kk * 9 + (c >> 1)] = (unsigned)f2bf(v0) | ((unsigned)f2bf(v1) << 16);
        }
    }

    uint4* dst = (uint4*)(patch + ((size_t)(b * nchunk) + pl) * KP + g * GCH);
    #pragma unroll
    for (int i = 0; i < 22; ++i)
        dst[i] = make_uint4(u[4*i], u[4*i+1], u[4*i+2], u[4*i+3]);
}

// ---------------- MFMA bf16 dcn GEMM: C[180,n] += A[192,KP] * patch^T ----------------
__global__ __launch_bounds__(256)
void dgemm_k(const unsigned short* __restrict__ A, const unsigned short* __restrict__ patch,
             const float* __restrict__ bias, float* __restrict__ C, int nchunk, int p0)
{
    __shared__ uint4 smem[1024];                 // 12KB A-tile + 4KB B-tile
    char* lds = (char*)smem;
    const int b = blockIdx.z, n0 = blockIdx.x * 64;
    const int tid = threadIdx.x;
    const int wv = tid >> 6, l = tid & 63;
    const int lg = l >> 4, lm = l & 15;
    const int arow = tid >> 2, aseg = tid & 3;

    const unsigned short* Ag = A + (size_t)arow * KP + aseg * 8;
    const unsigned short* Bg = patch + ((size_t)(b * nchunk + n0 + arow)) * KP + aseg * 8;

    int wbA[3], wmA[3];
    #pragma unroll
    for (int i = 0; i < 3; ++i) {
        int row = arow + (i << 6);
        wbA[i] = row << 6;
        wmA[i] = (aseg << 4) ^ (((row & 3) << 4) | ((row & 4) << 1));
    }
    const int wbB = 12288 + (arow << 6);
    const int wmB = (aseg << 4) ^ (((arow & 3) << 4) | ((arow & 4) << 1));

    int aoff[3][2], boff[4][2];
    #pragma unroll
    for (int fr = 0; fr < 3; ++fr) {
        int row = wv * 48 + fr * 16 + lm;
        int m = ((row & 3) << 4) | ((row & 4) << 1);
        aoff[fr][0] = (row << 6) + (((lg << 3)     ) ^ m);
        aoff[fr][1] = (row << 6) + (((lg << 3) + 32) ^ m);
    }
    #pragma unroll
    for (int nc = 0; nc < 4; ++nc) {
        int n = nc * 16 + lm;
        int m = ((n & 3) << 4) | ((n & 4) << 1);
        boff[nc][0] = 12288 + (n << 6) + (((lg << 3)     ) ^ m);
        boff[nc][1] = 12288 + (n << 6) + (((lg << 3) + 32) ^ m);
    }

    uint4 ra0 = *(const uint4*)(Ag);
    uint4 ra1 = *(const uint4*)(Ag + (size_t)64 * KP);
    uint4 ra2 = *(const uint4*)(Ag + (size_t)128 * KP);
    uint4 rb  = *(const uint4*)(Bg);

    f32x4 acc[3][4];
    #pragma unroll
    for (int i = 0; i < 3; ++i)
        #pragma unroll
        for (int j = 0; j < 4; ++j)
            acc[i][j] = (f32x4){0.f, 0.f, 0.f, 0.f};

    for (int kt = 0; kt < KP / 32; ++kt) {
        __syncthreads();
        *(uint2*)(lds + wbA[0] + wmA[0])       = make_uint2(ra0.x, ra0.y);
        *(uint2*)(lds + wbA[0] + (wmA[0] ^ 8)) = make_uint2(ra0.z, ra0.w);
        *(uint2*)(lds + wbA[1] + wmA[1])       = make_uint2(ra1.x, ra1.y);
        *(uint2*)(lds + wbA[1] + (wmA[1] ^ 8)) = make_uint2(ra1.z, ra1.w);
        *(uint2*)(lds + wbA[2] + wmA[2])       = make_uint2(ra2.x, ra2.y);
        *(uint2*)(lds + wbA[2] + (wmA[2] ^ 8)) = make_uint2(ra2.z, ra2.w);
        *(uint2*)(lds + wbB + wmB)             = make_uint2(rb.x, rb.y);
        *(uint2*)(lds + wbB + (wmB ^ 8))       = make_uint2(rb.z, rb.w);
        __syncthreads();

        if (kt < KP / 32 - 1) {
            int k0 = (kt + 1) * 32;
            ra0 = *(const uint4*)(Ag + k0);
            ra1 = *(const uint4*)(Ag + (size_t)64 * KP + k0);
            ra2 = *(const uint4*)(Ag + (size_t)128 * KP + k0);
            rb  = *(const uint4*)(Bg + k0);
        }

        FragU af[3], bf[4];
        #pragma unroll
        for (int fr = 0; fr < 3; ++fr) {
            af[fr].u2[0] = *(const uint2*)(lds + aoff[fr][0]);
            af[fr].u2[1] = *(const uint2*)(lds + aoff[fr][1]);
        }
        #pragma unroll
        for (int nc = 0; nc < 4; ++nc) {
            bf[nc].u2[0] = *(const uint2*)(lds + boff[nc][0]);
            bf[nc].u2[1] = *(const uint2*)(lds + boff[nc][1]);
        }
        #pragma unroll
        for (int fr = 0; fr < 3; ++fr)
            #pragma unroll
            for (int nc = 0; nc < 4; ++nc)
                acc[fr][nc] = __builtin_amdgcn_mfma_f32_16x16x32_bf16(
                    af[fr].v, bf[nc].v, acc[fr][nc], 0, 0, 0);
    }

    #pragma unroll
    for (int fr = 0; fr < 3; ++fr) {
        #pragma unroll
        for (int r = 0; r < 4; ++r) {
            int rr = wv * 48 + fr * 16 + lg * 4 + r;
            if (rr < CMID) {
                float bi = bias[rr];
                float* Cr = C + (size_t)b * CMID * HW + (size_t)rr * HW + p0 + n0 + lm;
                #pragma unroll
                for (int nc = 0; nc < 4; ++nc)
                    Cr[nc * 16] = acc[fr][nc][r] + bi;
            }
        }
    }
}

// ---------------- mean over HW of (f_w + f_h) ----------------
__global__ __launch_bounds__(256)
void avg_k(const float* __restrict__ fw, const float* __restrict__ fh,
           float* __restrict__ favg)
{
    const int bm = blockIdx.x;
    const size_t base = (size_t)bm * HW;
    float s = 0.f;
    for (int i = threadIdx.x; i < HW; i += 256)
        s += fw[base + i] + fh[base + i];
    #pragma unroll
    for (int off = 32; off > 0; off >>= 1) s += __shfl_down(s, off, 64);
    __shared__ float sb[4];
    const int tid = threadIdx.x;
    if ((tid & 63) == 0) sb[tid >> 6] = s;
    __syncthreads();
    if (tid == 0) favg[bm] = (sb[0] + sb[1] + sb[2] + sb[3]) / (float)HW;
}

// ---------------- attention softmax ----------------
__global__ __launch_bounds__(256)
void attn_k(const float* __restrict__ favg, const float* __restrict__ w_attn,
            const float* __restrict__ b_attn, float* __restrict__ attnb)
{
    const int b = blockIdx.x;
    const int t = threadIdx.x;
    float z0 = 0.f, z1 = 0.f;
    if (t < CMID) {
        float f = favg[b * CMID + t];
        z0 = w_attn[t] * f;
        z1 = w_attn[CMID + t] * f;
    }
    #pragma unroll
    for (int off = 32; off > 0; off >>= 1) {
        z0 += __shfl_down(z0, off, 64);
        z1 += __shfl_down(z1, off, 64);
    }
    __shared__ float s0[4], s1[4];
    if ((t & 63) == 0) { s0[t >> 6] = z0; s1[t >> 6] = z1; }
    __syncthreads();
    if (t == 0) {
        float a = s0[0] + s0[1] + s0[2] + s0[3] + b_attn[0];
        float c = s1[0] + s1[1] + s1[2] + s1[3] + b_attn[1];
        float m = fmaxf(a, c);
        float e0 = expf(a - m), e1 = expf(c - m);
        float inv = 1.f / (e0 + e1);
        attnb[2 * b + 0] = e0 * inv;   // multiplies f_h
        attnb[2 * b + 1] = e1 * inv;   // multiplies f_w
    }
}

extern "C" void kernel_launch(void* const* d_in, const int* in_sizes, int n_in,
                              void* d_out, int out_size, void* d_ws, size_t ws_size,
                              hipStream_t stream) {
    const float* x        = (const float*)d_in[0];
    const float* w_reduce = (const float*)d_in[1];
    const float* b_reduce = (const float*)d_in[2];
    const float* w_offset = (const float*)d_in[3];
    const float* b_offset = (const float*)d_in[4];
    const float* w_dcnw   = (const float*)d_in[5];
    const float* b_dcnw   = (const float*)d_in[6];
    const float* w_dcnh   = (const float*)d_in[7];
    const float* b_dcnh   = (const float*)d_in[8];
    const float* w_expand = (const float*)d_in[9];
    const float* b_expand = (const float*)d_in[10];
    const float* w_attn   = (const float*)d_in[11];
    const float* b_attn   = (const float*)d_in[12];
    float* out = (float*)d_out;

    // workspace layout
    char* base = (char*)d_ws;
    size_t o = 0;
    float* xr    = (float*)(base + o); o += (size_t)NB * CMID * HW * 4;
    float* offs  = (float*)(base + o); o += (size_t)NB * 2 * CMID * HW * 4;
    float* fw    = (float*)(base + o); o += (size_t)NB * CMID * HW * 4;
    float* fh    = (float*)(base + o); o += (size_t)NB * CMID * HW * 4;
    float* favg  = (float*)(base + o); o += (size_t)NB * CMID * 4;
    float* attnb = (float*)(base + o); o += 32;
    float* xrt   = (float*)(base + o); o += (size_t)NB * NG * HW * CP * 4;   // 14.75 MB
    unsigned short* wbf = (unsigned short*)(base + o); o += (size_t)2 * MP * KP * 2;
    unsigned short* patch = (unsigned short*)(base + o);

    int nchunk = 2304;
    const int cand[3] = {9216, 4608, 2304};        // all divisible by 256
    for (int i = 0; i < 3; ++i) {
        size_t need = o + (size_t)NB * cand[i] * KP * 2;
        if (need <= ws_size) { nchunk = cand[i]; break; }
    }

    // 0) convert dcn weights to tap-major padded bf16 layout
    convw5_k<<<dim3((2 * MP * KP) / 256), 256, 0, stream>>>(w_dcnw, w_dcnh, wbf);

    // 1) xr = w_reduce @ x + b_reduce  (+ channel-last xrt scatter)
    gemm_k<false, true><<<dim3(3, HW / 64, NB), 256, 0, stream>>>(
        w_reduce, x, nullptr, nullptr, b_reduce, xr, xrt,
        CMID, HW, CIN, HW, HW, CIN * HW, CMID * HW);

    // 2) offs = w_offset @ xr + b_offset
    gemm_k<false, false><<<dim3(6, HW / 64, NB), 256, 0, stream>>>(
        w_offset, xr, nullptr, nullptr, b_offset, offs, nullptr,
        2 * CMID, HW, CMID, HW, HW, CMID * HW, 2 * CMID * HW);

    // 3) deformable convs via bf16 MFMA: set0 -> f_w (w_dcnw), set1 -> f_h (w_dcnh)
    for (int set = 0; set < 2; ++set) {
        const float* bD = set ? b_dcnh : b_dcnw;
        float* fD = set ? fh : fw;
        for (int p0 = 0; p0 < HW; p0 += nchunk) {
            gather5_k<<<dim3(nchunk / 256, NG, NB), 256, 0, stream>>>(
                xrt, offs, patch, set, p0, nchunk);
            dgemm_k<<<dim3(nchunk / 64, 1, NB), 256, 0, stream>>>(
                wbf + (size_t)set * MP * KP, patch, bD, fD, nchunk, p0);
        }
    }

    // 4) f_avg = mean_HW(f_w + f_h)
    avg_k<<<dim3(NB * CMID), 256, 0, stream>>>(fw, fh, favg);

    // 5) attn = softmax(w_attn @ f_avg + b_attn)
    attn_k<<<dim3(NB), 256, 0, stream>>>(favg, w_attn, b_attn, attnb);

    // 6) out = w_expand @ (a0*f_h + a1*f_w) + b_expand
    gemm_k<true, false><<<dim3(3, HW / 64, NB), 256, 0, stream>>>(
        w_expand, fh, fw, attnb, b_expand, out, nullptr,
        CIN, HW, CMID, HW, HW, CMID * HW, CIN * HW);
}

// Round 12
// 409.903 us; speedup vs baseline: 1.3864x; 1.0893x over previous
//
#include <hip/hip_runtime.h>
#include <math.h>

#define HH 96
#define WW 96
#define HW 9216
#define CIN 192
#define CMID 180
#define NB 2
#define NG 10
#define KTAPS 9
#define KP 1760         // padded K: 10 groups x 176; per group tap-major: kr = kk*18 + c, 162 real
#define GCH 176
#define NDW 880         // KP/2 dwords per pixel
#define MP 192          // padded M for dcn GEMM
#define CP 20           // padded channel-last row (18 floats + 2 pad) = 80 B

typedef __attribute__((ext_vector_type(8))) short short8;
typedef __attribute__((ext_vector_type(4))) float f32x4;
union FragU { uint2 u2[2]; short8 v; };

static __device__ inline unsigned short f2bf(float f) {
    unsigned x = __float_as_uint(f);
    unsigned r = (x + 0x7fffu + ((x >> 16) & 1u)) >> 16;   // RNE
    return (unsigned short)r;
}
#define SWZ(r) ((((r) & 3) << 4) | (((r) & 4) << 1))

// ---------------- generic tiled fp32 GEMM (reduce / offset / expand) ----------------
// XT: also scatter C into channel-last xrt[b][g][n][CP] (reduce conv only)
template<bool COMBINE, bool XT>
__global__ __launch_bounds__(256)
void gemm_k(const float* __restrict__ A,
            const float* __restrict__ B0, const float* __restrict__ B1,
            const float* __restrict__ attnb,
            const float* __restrict__ bias, float* __restrict__ C,
            float* __restrict__ xrt,
            int M, int N, int K, int ldb, int ldc, int bsB, int bsC)
{
    const int b = blockIdx.z;
    const float* Bp0 = B0 + (size_t)b * bsB;
    const float* Bp1 = COMBINE ? (B1 + (size_t)b * bsB) : nullptr;
    float* Cp = C + (size_t)b * bsC;
    float a0 = 0.f, a1 = 0.f;
    if (COMBINE) { a0 = attnb[2*b]; a1 = attnb[2*b+1]; }

    __shared__ float As[16][68];
    __shared__ float Bs[16][64];

    const int tid = threadIdx.x;
    const int m0 = blockIdx.x * 64, n0 = blockIdx.y * 64;
    const int am = tid >> 2, ak = (tid & 3) << 2;
    const int bk = tid >> 4, bn = (tid & 15) << 2;
    const int ty = tid >> 4, tx = tid & 15;

    float acc[4][4] = {};

    for (int k0 = 0; k0 < K; k0 += 16) {
        float4 av = make_float4(0.f, 0.f, 0.f, 0.f);
        if ((m0 + am) < M && (k0 + ak) < K)
            av = *reinterpret_cast<const float4*>(A + (size_t)(m0 + am) * K + k0 + ak);
        As[ak + 0][am] = av.x; As[ak + 1][am] = av.y;
        As[ak + 2][am] = av.z; As[ak + 3][am] = av.w;

        float4 bv = make_float4(0.f, 0.f, 0.f, 0.f);
        if ((k0 + bk) < K) {
            size_t o = (size_t)(k0 + bk) * ldb + n0 + bn;
            bv = *reinterpret_cast<const float4*>(Bp0 + o);
            if (COMBINE) {
                float4 c4 = *reinterpret_cast<const float4*>(Bp1 + o);
                bv.x = a0 * bv.x + a1 * c4.x; bv.y = a0 * bv.y + a1 * c4.y;
                bv.z = a0 * bv.z + a1 * c4.z; bv.w = a0 * bv.w + a1 * c4.w;
            }
        }
        *reinterpret_cast<float4*>(&Bs[bk][bn]) = bv;
        __syncthreads();

        #pragma unroll
        for (int kk = 0; kk < 16; ++kk) {
            float4 a  = *reinterpret_cast<const float4*>(&As[kk][ty << 2]);
            float4 bb = *reinterpret_cast<const float4*>(&Bs[kk][tx << 2]);
            acc[0][0] += a.x * bb.x; acc[0][1] += a.x * bb.y; acc[0][2] += a.x * bb.z; acc[0][3] += a.x * bb.w;
            acc[1][0] += a.y * bb.x; acc[1][1] += a.y * bb.y; acc[1][2] += a.y * bb.z; acc[1][3] += a.y * bb.w;
            acc[2][0] += a.z * bb.x; acc[2][1] += a.z * bb.y; acc[2][2] += a.z * bb.z; acc[2][3] += a.z * bb.w;
            acc[3][0] += a.w * bb.x; acc[3][1] += a.w * bb.y; acc[3][2] += a.w * bb.z; acc[3][3] += a.w * bb.w;
        }
        __syncthreads();
    }

    #pragma unroll
    for (int i = 0; i < 4; ++i) {
        int m = m0 + (ty << 2) + i;
        if (m < M) {
            float bi = bias[m];
            #pragma unroll
            for (int j = 0; j < 4; ++j) {
                float s = acc[i][j] + bi;
                int n = n0 + (tx << 2) + j;
                Cp[(size_t)m * ldc + n] = s;
                if (XT)
                    xrt[((size_t)(b * NG + m / 18) * HW + n) * CP + (m % 18)] = s;
            }
        }
    }
}

// ---------------- weight convert to tap-major padded bf16 [2][192][KP] ----------------
__global__ __launch_bounds__(256)
void convw5_k(const float* __restrict__ w0, const float* __restrict__ w1,
              unsigned short* __restrict__ wbf)
{
    int idx = blockIdx.x * 256 + threadIdx.x;      // 2*192*1760 = 675840
    int set = idx / (MP * KP);
    int r0 = idx - set * MP * KP;
    int o = r0 / KP, k = r0 - o * KP;
    int g = k / GCH, kr = k - g * GCH;
    float v = 0.f;
    if (o < CMID && kr < 162) {
        int kk = kr / 18, c = kr % 18;
        v = (set ? w1 : w0)[((size_t)o * CMID + g * 18 + c) * KTAPS + kk];
    }
    wbf[idx] = f2bf(v);
}

// ---------------- deformable im2col gather, channel-last source ----------------
// Thread = (pixel, group). Loads: 4 corners x 18ch as float4/float2 (<=2 lines each).
// Stores: patch2[b][dw][pix] dword-row layout -> 88 dword stores, 64 lanes x 4B
// = fully-covered 256B bursts (ZERO write amplification; fixes R9's 7x RMW).
__global__ __launch_bounds__(256)
void gather6_k(const float* __restrict__ xrt, const float* __restrict__ offs,
               unsigned* __restrict__ patch2, int set, int p0, int nchunk)
{
    const int b = blockIdx.z;
    const int g = blockIdx.y;                        // 0..9
    const int pl = blockIdx.x * 256 + threadIdx.x;   // pixel within chunk
    const int pix = p0 + pl;
    const int h = pix / WW, w = pix % WW;

    const float* ob = offs + (((size_t)b * 2 + set) * CMID + g * 18) * HW + pix;
    float oyA[9], oxA[9];
    #pragma unroll
    for (int kk = 0; kk < 9; ++kk) {
        oyA[kk] = ob[(size_t)(2 * kk) * HW];
        oxA[kk] = ob[(size_t)(2 * kk + 1) * HW];
    }

    const float* gbase = xrt + (size_t)(b * NG + g) * HW * CP;
    unsigned u[88];
    #pragma unroll
    for (int i = 81; i < 88; ++i) u[i] = 0u;         // pad elems 162..175

    #pragma unroll
    for (int kk = 0; kk < 9; ++kk) {
        float sy = oyA[kk] + (float)(kk / 3 - 1 + h);
        float sx = oxA[kk] + (float)(kk % 3 - 1 + w);
        float yf = floorf(sy), xf = floorf(sx);
        float dy = sy - yf, dx = sx - xf;
        int y0 = (int)yf, x0 = (int)xf;
        bool vy0 = (unsigned)y0 < (unsigned)HH, vy1 = (unsigned)(y0 + 1) < (unsigned)HH;
        bool vx0 = (unsigned)x0 < (unsigned)WW, vx1 = (unsigned)(x0 + 1) < (unsigned)WW;
        int yc0 = min(max(y0, 0), HH - 1), yc1 = min(max(y0 + 1, 0), HH - 1);
        int xc0 = min(max(x0, 0), WW - 1), xc1 = min(max(x0 + 1, 0), WW - 1);
        float w00 = (1.f - dy) * (1.f - dx) * ((vy0 && vx0) ? 1.f : 0.f);
        float w01 = (1.f - dy) * dx         * ((vy0 && vx1) ? 1.f : 0.f);
        float w10 = dy * (1.f - dx)         * ((vy1 && vx0) ? 1.f : 0.f);
        float w11 = dy * dx                 * ((vy1 && vx1) ? 1.f : 0.f);

        const float* r00 = gbase + (size_t)(yc0 * WW + xc0) * CP;
        const float* r01 = gbase + (size_t)(yc0 * WW + xc1) * CP;
        const float* r10 = gbase + (size_t)(yc1 * WW + xc0) * CP;
        const float* r11 = gbase + (size_t)(yc1 * WW + xc1) * CP;

        float A00[18], A01[18], A10[18], A11[18];
        #pragma unroll
        for (int q = 0; q < 4; ++q) {
            *reinterpret_cast<float4*>(&A00[q * 4]) = *reinterpret_cast<const float4*>(r00 + q * 4);
            *reinterpret_cast<float4*>(&A01[q * 4]) = *reinterpret_cast<const float4*>(r01 + q * 4);
            *reinterpret_cast<float4*>(&A10[q * 4]) = *reinterpret_cast<const float4*>(r10 + q * 4);
            *reinterpret_cast<float4*>(&A11[q * 4]) = *reinterpret_cast<const float4*>(r11 + q * 4);
        }
        *reinterpret_cast<float2*>(&A00[16]) = *reinterpret_cast<const float2*>(r00 + 16);
        *reinterpret_cast<float2*>(&A01[16]) = *reinterpret_cast<const float2*>(r01 + 16);
        *reinterpret_cast<float2*>(&A10[16]) = *reinterpret_cast<const float2*>(r10 + 16);
        *reinterpret_cast<float2*>(&A11[16]) = *reinterpret_cast<const float2*>(r11 + 16);

        #pragma unroll
        for (int c = 0; c < 18; c += 2) {
            float v0 = w00 * A00[c]     + w01 * A01[c]     + w10 * A10[c]     + w11 * A11[c];
            float v1 = w00 * A00[c + 1] + w01 * A01[c + 1] + w10 * A10[c + 1] + w11 * A11[c + 1];
            u[kk * 9 + (c >> 1)] = (unsigned)f2bf(v0) | ((unsigned)f2bf(v1) << 16);
        }
    }

    // coalesced dword-row stores
    unsigned* dst = patch2 + ((size_t)(b * NDW) + g * 88) * nchunk + pl;
    #pragma unroll
    for (int i = 0; i < 88; ++i)
        dst[(size_t)i * nchunk] = u[i];
}

// ---------------- MFMA bf16 dcn GEMM: C[180,n] += A[192,KP] * patch2^T ----------------
// B source: patch2[b][dw][pix]. Thread (bdw=tid&15, bpq=tid>>4) loads uint4 =
// 4 consecutive pixels' dword bdw; writes 4x ds_write_b32 at (4*bdw)^SWZ(n) --
// reproduces the exact LDS byte image of the old layout (byte beta at beta^SWZ(n)).
__global__ __launch_bounds__(256)
void dgemm_k(const unsigned short* __restrict__ A, const unsigned* __restrict__ patch2,
             const float* __restrict__ bias, float* __restrict__ C, int nchunk, int p0)
{
    __shared__ uint4 smem[1024];                 // 12KB A-tile + 4KB B-tile
    char* lds = (char*)smem;
    const int b = blockIdx.z, n0 = blockIdx.x * 64;
    const int tid = threadIdx.x;
    const int wv = tid >> 6, l = tid & 63;
    const int lg = l >> 4, lm = l & 15;
    const int arow = tid >> 2, aseg = tid & 3;
    const int bdw = tid & 15, bpq = tid >> 4;

    const unsigned short* Ag = A + (size_t)arow * KP + aseg * 8;
    const unsigned* Bg = patch2 + (size_t)(b * NDW) * nchunk + n0 + 4 * bpq;

    int wbA[3], wmA[3];
    #pragma unroll
    for (int i = 0; i < 3; ++i) {
        int row = arow + (i << 6);
        wbA[i] = row << 6;
        wmA[i] = (aseg << 4) ^ SWZ(row);
    }
    // B LDS write addresses (4 rows per thread)
    int wB[4];
    #pragma unroll
    for (int i = 0; i < 4; ++i) {
        int n = bpq * 4 + i;
        wB[i] = 12288 + (n << 6) + ((bdw << 2) ^ SWZ(n));
    }

    int aoff[3][2], boff[4][2];
    #pragma unroll
    for (int fr = 0; fr < 3; ++fr) {
        int row = wv * 48 + fr * 16 + lm;
        int m = SWZ(row);
        aoff[fr][0] = (row << 6) + (((lg << 3)     ) ^ m);
        aoff[fr][1] = (row << 6) + (((lg << 3) + 32) ^ m);
    }
    #pragma unroll
    for (int nc = 0; nc < 4; ++nc) {
        int n = nc * 16 + lm;
        int m = SWZ(n);
        boff[nc][0] = 12288 + (n << 6) + (((lg << 3)     ) ^ m);
        boff[nc][1] = 12288 + (n << 6) + (((lg << 3) + 32) ^ m);
    }

    uint4 ra0 = *(const uint4*)(Ag);
    uint4 ra1 = *(const uint4*)(Ag + (size_t)64 * KP);
    uint4 ra2 = *(const uint4*)(Ag + (size_t)128 * KP);
    uint4 rb  = *(const uint4*)(Bg + (size_t)bdw * nchunk);

    f32x4 acc[3][4];
    #pragma unroll
    for (int i = 0; i < 3; ++i)
        #pragma unroll
        for (int j = 0; j < 4; ++j)
            acc[i][j] = (f32x4){0.f, 0.f, 0.f, 0.f};

    for (int kt = 0; kt < KP / 32; ++kt) {
        __syncthreads();
        *(uint2*)(lds + wbA[0] + wmA[0])       = make_uint2(ra0.x, ra0.y);
        *(uint2*)(lds + wbA[0] + (wmA[0] ^ 8)) = make_uint2(ra0.z, ra0.w);
        *(uint2*)(lds + wbA[1] + wmA[1])       = make_uint2(ra1.x, ra1.y);
        *(uint2*)(lds + wbA[1] + (wmA[1] ^ 8)) = make_uint2(ra1.z, ra1.w);
        *(uint2*)(lds + wbA[2] + wmA[2])       = make_uint2(ra2.x, ra2.y);
        *(uint2*)(lds + wbA[2] + (wmA[2] ^ 8)) = make_uint2(ra2.z, ra2.w);
        *(unsigned*)(lds + wB[0]) = rb.x;
        *(unsigned*)(lds + wB[1]) = rb.y;
        *(unsigned*)(lds + wB[2]) = rb.z;
        *(unsigned*)(lds + wB[3]) = rb.w;
        __syncthreads();

        if (kt < KP / 32 - 1) {
            int k0 = (kt + 1) * 32;
            ra0 = *(const uint4*)(Ag + k0);
            ra1 = *(const uint4*)(Ag + (size_t)64 * KP + k0);
            ra2 = *(const uint4*)(Ag + (size_t)128 * KP + k0);
            rb  = *(const uint4*)(Bg + (size_t)((kt + 1) * 16 + bdw) * nchunk);
        }

        FragU af[3], bf[4];
        #pragma unroll
        for (int fr = 0; fr < 3; ++fr) {
            af[fr].u2[0] = *(const uint2*)(lds + aoff[fr][0]);
            af[fr].u2[1] = *(const uint2*)(lds + aoff[fr][1]);
        }
        #pragma unroll
        for (int nc = 0; nc < 4; ++nc) {
            bf[nc].u2[0] = *(const uint2*)(lds + boff[nc][0]);
            bf[nc].u2[1] = *(const uint2*)(lds + boff[nc][1]);
        }
        #pragma unroll
        for (int fr = 0; fr < 3; ++fr)
            #pragma unroll
            for (int nc = 0; nc < 4; ++nc)
                acc[fr][nc] = __builtin_amdgcn_mfma_f32_16x16x32_bf16(
                    af[fr].v, bf[nc].v, acc[fr][nc], 0, 0, 0);
    }

    #pragma unroll
    for (int fr = 0; fr < 3; ++fr) {
        #pragma unroll
        for (int r = 0; r < 4; ++r) {
            int rr = wv * 48 + fr * 16 + lg * 4 + r;
            if (rr < CMID) {
                float bi = bias[rr];
                float* Cr = C + (size_t)b * CMID * HW + (size_t)rr * HW + p0 + n0 + lm;
                #pragma unroll
                for (int nc = 0; nc < 4; ++nc)
                    Cr[nc * 16] = acc[fr][nc][r] + bi;
            }
        }
    }
}

// ---------------- mean over HW of (f_w + f_h) ----------------
__global__ __launch_bounds__(256)
void avg_k(const float* __restrict__ fw, const float* __restrict__ fh,
           float* __restrict__ favg)
{
    const int bm = blockIdx.x;
    const size_t base = (size_t)bm * HW;
    float s = 0.f;
    for (int i = threadIdx.x; i < HW; i += 256)
        s += fw[base + i] + fh[base + i];
    #pragma unroll
    for (int off = 32; off > 0; off >>= 1) s += __shfl_down(s, off, 64);
    __shared__ float sb[4];
    const int tid = threadIdx.x;
    if ((tid & 63) == 0) sb[tid >> 6] = s;
    __syncthreads();
    if (tid == 0) favg[bm] = (sb[0] + sb[1] + sb[2] + sb[3]) / (float)HW;
}

// ---------------- attention softmax ----------------
__global__ __launch_bounds__(256)
void attn_k(const float* __restrict__ favg, const float* __restrict__ w_attn,
            const float* __restrict__ b_attn, float* __restrict__ attnb)
{
    const int b = blockIdx.x;
    const int t = threadIdx.x;
    float z0 = 0.f, z1 = 0.f;
    if (t < CMID) {
        float f = favg[b * CMID + t];
        z0 = w_attn[t] * f;
        z1 = w_attn[CMID + t] * f;
    }
    #pragma unroll
    for (int off = 32; off > 0; off >>= 1) {
        z0 += __shfl_down(z0, off, 64);
        z1 += __shfl_down(z1, off, 64);
    }
    __shared__ float s0[4], s1[4];
    if ((t & 63) == 0) { s0[t >> 6] = z0; s1[t >> 6] = z1; }
    __syncthreads();
    if (t == 0) {
        float a = s0[0] + s0[1] + s0[2] + s0[3] + b_attn[0];
        float c = s1[0] + s1[1] + s1[2] + s1[3] + b_attn[1];
        float m = fmaxf(a, c);
        float e0 = expf(a - m), e1 = expf(c - m);
        float inv = 1.f / (e0 + e1);
        attnb[2 * b + 0] = e0 * inv;   // multiplies f_h
        attnb[2 * b + 1] = e1 * inv;   // multiplies f_w
    }
}

extern "C" void kernel_launch(void* const* d_in, const int* in_sizes, int n_in,
                              void* d_out, int out_size, void* d_ws, size_t ws_size,
                              hipStream_t stream) {
    const float* x        = (const float*)d_in[0];
    const float* w_reduce = (const float*)d_in[1];
    const float* b_reduce = (const float*)d_in[2];
    const float* w_offset = (const float*)d_in[3];
    const float* b_offset = (const float*)d_in[4];
    const float* w_dcnw   = (const float*)d_in[5];
    const float* b_dcnw   = (const float*)d_in[6];
    const float* w_dcnh   = (const float*)d_in[7];
    const float* b_dcnh   = (const float*)d_in[8];
    const float* w_expand = (const float*)d_in[9];
    const float* b_expand = (const float*)d_in[10];
    const float* w_attn   = (const float*)d_in[11];
    const float* b_attn   = (const float*)d_in[12];
    float* out = (float*)d_out;

    // workspace layout
    char* base = (char*)d_ws;
    size_t o = 0;
    float* xr    = (float*)(base + o); o += (size_t)NB * CMID * HW * 4;
    float* offs  = (float*)(base + o); o += (size_t)NB * 2 * CMID * HW * 4;
    float* fw    = (float*)(base + o); o += (size_t)NB * CMID * HW * 4;
    float* fh    = (float*)(base + o); o += (size_t)NB * CMID * HW * 4;
    float* favg  = (float*)(base + o); o += (size_t)NB * CMID * 4;
    float* attnb = (float*)(base + o); o += 32;
    float* xrt   = (float*)(base + o); o += (size_t)NB * NG * HW * CP * 4;   // 14.75 MB
    unsigned short* wbf = (unsigned short*)(base + o); o += (size_t)2 * MP * KP * 2;
    unsigned* patch2 = (unsigned*)(base + o);

    int nchunk = 2304;
    const int cand[3] = {9216, 4608, 2304};        // all divisible by 256
    for (int i = 0; i < 3; ++i) {
        size_t need = o + (size_t)NB * cand[i] * KP * 2;
        if (need <= ws_size) { nchunk = cand[i]; break; }
    }

    // 0) convert dcn weights to tap-major padded bf16 layout
    convw5_k<<<dim3((2 * MP * KP) / 256), 256, 0, stream>>>(w_dcnw, w_dcnh, wbf);

    // 1) xr = w_reduce @ x + b_reduce  (+ channel-last xrt scatter)
    gemm_k<false, true><<<dim3(3, HW / 64, NB), 256, 0, stream>>>(
        w_reduce, x, nullptr, nullptr, b_reduce, xr, xrt,
        CMID, HW, CIN, HW, HW, CIN * HW, CMID * HW);

    // 2) offs = w_offset @ xr + b_offset
    gemm_k<false, false><<<dim3(6, HW / 64, NB), 256, 0, stream>>>(
        w_offset, xr, nullptr, nullptr, b_offset, offs, nullptr,
        2 * CMID, HW, CMID, HW, HW, CMID * HW, 2 * CMID * HW);

    // 3) deformable convs via bf16 MFMA: set0 -> f_w (w_dcnw), set1 -> f_h (w_dcnh)
    for (int set = 0; set < 2; ++set) {
        const float* bD = set ? b_dcnh : b_dcnw;
        float* fD = set ? fh : fw;
        for (int p0 = 0; p0 < HW; p0 += nchunk) {
            gather6_k<<<dim3(nchunk / 256, NG, NB), 256, 0, stream>>>(
                xrt, offs, patch2, set, p0, nchunk);
            dgemm_k<<<dim3(nchunk / 64, 1, NB), 256, 0, stream>>>(
                wbf + (size_t)set * MP * KP, patch2, bD, fD, nchunk, p0);
        }
    }

    // 4) f_avg = mean_HW(f_w + f_h)
    avg_k<<<dim3(NB * CMID), 256, 0, stream>>>(fw, fh, favg);

    // 5) attn = softmax(w_attn @ f_avg + b_attn)
    attn_k<<<dim3(NB), 256, 0, stream>>>(favg, w_attn, b_attn, attnb);

    // 6) out = w_expand @ (a0*f_h + a1*f_w) + b_expand
    gemm_k<true, false><<<dim3(3, HW / 64, NB), 256, 0, stream>>>(
        w_expand, fh, fw, attnb, b_expand, out, nullptr,
        CIN, HW, CMID, HW, HW, CMID * HW, CIN * HW);
}

// Round 13
// 364.847 us; speedup vs baseline: 1.5576x; 1.1235x over previous
//
#include <hip/hip_runtime.h>
#include <math.h>

#define HH 96
#define WW 96
#define HW 9216
#define CIN 192
#define CMID 180
#define NB 2
#define NG 10
#define KTAPS 9
#define KP 1760         // padded K: 10 groups x 176; per group tap-major: kr = kk*18 + c, 162 real
#define GCH 176
#define NDW 880         // KP/2 dwords per pixel
#define MP 192          // padded M for dcn GEMM
#define CP 20           // padded channel-last row (18 floats + 2 pad) = 80 B

typedef __attribute__((ext_vector_type(8))) short short8;
typedef __attribute__((ext_vector_type(4))) float f32x4;
union FragU { uint2 u2[2]; short8 v; };

static __device__ inline unsigned short f2bf(float f) {
    unsigned x = __float_as_uint(f);
    unsigned r = (x + 0x7fffu + ((x >> 16) & 1u)) >> 16;   // RNE
    return (unsigned short)r;
}
#define SWZ(r) ((((r) & 3) << 4) | (((r) & 4) << 1))

// ---------------- generic tiled fp32 GEMM (reduce / offset / expand) ----------------
// XT: also scatter C into channel-last xrt[b][g][n][CP] (reduce conv only)
template<bool COMBINE, bool XT>
__global__ __launch_bounds__(256)
void gemm_k(const float* __restrict__ A,
            const float* __restrict__ B0, const float* __restrict__ B1,
            const float* __restrict__ attnb,
            const float* __restrict__ bias, float* __restrict__ C,
            float* __restrict__ xrt,
            int M, int N, int K, int ldb, int ldc, int bsB, int bsC)
{
    const int b = blockIdx.z;
    const float* Bp0 = B0 + (size_t)b * bsB;
    const float* Bp1 = COMBINE ? (B1 + (size_t)b * bsB) : nullptr;
    float* Cp = C + (size_t)b * bsC;
    float a0 = 0.f, a1 = 0.f;
    if (COMBINE) { a0 = attnb[2*b]; a1 = attnb[2*b+1]; }

    __shared__ float As[16][68];
    __shared__ float Bs[16][64];

    const int tid = threadIdx.x;
    const int m0 = blockIdx.x * 64, n0 = blockIdx.y * 64;
    const int am = tid >> 2, ak = (tid & 3) << 2;
    const int bk = tid >> 4, bn = (tid & 15) << 2;
    const int ty = tid >> 4, tx = tid & 15;

    float acc[4][4] = {};

    for (int k0 = 0; k0 < K; k0 += 16) {
        float4 av = make_float4(0.f, 0.f, 0.f, 0.f);
        if ((m0 + am) < M && (k0 + ak) < K)
            av = *reinterpret_cast<const float4*>(A + (size_t)(m0 + am) * K + k0 + ak);
        As[ak + 0][am] = av.x; As[ak + 1][am] = av.y;
        As[ak + 2][am] = av.z; As[ak + 3][am] = av.w;

        float4 bv = make_float4(0.f, 0.f, 0.f, 0.f);
        if ((k0 + bk) < K) {
            size_t o = (size_t)(k0 + bk) * ldb + n0 + bn;
            bv = *reinterpret_cast<const float4*>(Bp0 + o);
            if (COMBINE) {
                float4 c4 = *reinterpret_cast<const float4*>(Bp1 + o);
                bv.x = a0 * bv.x + a1 * c4.x; bv.y = a0 * bv.y + a1 * c4.y;
                bv.z = a0 * bv.z + a1 * c4.z; bv.w = a0 * bv.w + a1 * c4.w;
            }
        }
        *reinterpret_cast<float4*>(&Bs[bk][bn]) = bv;
        __syncthreads();

        #pragma unroll
        for (int kk = 0; kk < 16; ++kk) {
            float4 a  = *reinterpret_cast<const float4*>(&As[kk][ty << 2]);
            float4 bb = *reinterpret_cast<const float4*>(&Bs[kk][tx << 2]);
            acc[0][0] += a.x * bb.x; acc[0][1] += a.x * bb.y; acc[0][2] += a.x * bb.z; acc[0][3] += a.x * bb.w;
            acc[1][0] += a.y * bb.x; acc[1][1] += a.y * bb.y; acc[1][2] += a.y * bb.z; acc[1][3] += a.y * bb.w;
            acc[2][0] += a.z * bb.x; acc[2][1] += a.z * bb.y; acc[2][2] += a.z * bb.z; acc[2][3] += a.z * bb.w;
            acc[3][0] += a.w * bb.x; acc[3][1] += a.w * bb.y; acc[3][2] += a.w * bb.z; acc[3][3] += a.w * bb.w;
        }
        __syncthreads();
    }

    #pragma unroll
    for (int i = 0; i < 4; ++i) {
        int m = m0 + (ty << 2) + i;
        if (m < M) {
            float bi = bias[m];
            #pragma unroll
            for (int j = 0; j < 4; ++j) {
                float s = acc[i][j] + bi;
                int n = n0 + (tx << 2) + j;
                Cp[(size_t)m * ldc + n] = s;
                if (XT)
                    xrt[((size_t)(b * NG + m / 18) * HW + n) * CP + (m % 18)] = s;
            }
        }
    }
}

// ---------------- weight convert to tap-major padded bf16 [2][192][KP] ----------------
__global__ __launch_bounds__(256)
void convw5_k(const float* __restrict__ w0, const float* __restrict__ w1,
              unsigned short* __restrict__ wbf)
{
    int idx = blockIdx.x * 256 + threadIdx.x;      // 2*192*1760 = 675840
    int set = idx / (MP * KP);
    int r0 = idx - set * MP * KP;
    int o = r0 / KP, k = r0 - o * KP;
    int g = k / GCH, kr = k - g * GCH;
    float v = 0.f;
    if (o < CMID && kr < 162) {
        int kk = kr / 18, c = kr % 18;
        v = (set ? w1 : w0)[((size_t)o * CMID + g * 18 + c) * KTAPS + kk];
    }
    wbf[idx] = f2bf(v);
}

// ---------------- deformable im2col gather, channel-last source ----------------
// Both sets in one dispatch: blockIdx.z = b*2 + set. Coalesced dword-row stores.
__global__ __launch_bounds__(256)
void gather6_k(const float* __restrict__ xrt, const float* __restrict__ offs,
               unsigned* __restrict__ patch2, int p0, int nchunk)
{
    const int z = blockIdx.z;                        // b*2 + set
    const int b = z >> 1;
    const int g = blockIdx.y;                        // 0..9
    const int pl = blockIdx.x * 256 + threadIdx.x;   // pixel within chunk
    const int pix = p0 + pl;
    const int h = pix / WW, w = pix % WW;

    const float* ob = offs + ((size_t)z * CMID + g * 18) * HW + pix;
    float oyA[9], oxA[9];
    #pragma unroll
    for (int kk = 0; kk < 9; ++kk) {
        oyA[kk] = ob[(size_t)(2 * kk) * HW];
        oxA[kk] = ob[(size_t)(2 * kk + 1) * HW];
    }

    const float* gbase = xrt + (size_t)(b * NG + g) * HW * CP;
    unsigned u[88];
    #pragma unroll
    for (int i = 81; i < 88; ++i) u[i] = 0u;         // pad elems 162..175

    #pragma unroll
    for (int kk = 0; kk < 9; ++kk) {
        float sy = oyA[kk] + (float)(kk / 3 - 1 + h);
        float sx = oxA[kk] + (float)(kk % 3 - 1 + w);
        float yf = floorf(sy), xf = floorf(sx);
        float dy = sy - yf, dx = sx - xf;
        int y0 = (int)yf, x0 = (int)xf;
        bool vy0 = (unsigned)y0 < (unsigned)HH, vy1 = (unsigned)(y0 + 1) < (unsigned)HH;
        bool vx0 = (unsigned)x0 < (unsigned)WW, vx1 = (unsigned)(x0 + 1) < (unsigned)WW;
        int yc0 = min(max(y0, 0), HH - 1), yc1 = min(max(y0 + 1, 0), HH - 1);
        int xc0 = min(max(x0, 0), WW - 1), xc1 = min(max(x0 + 1, 0), WW - 1);
        float w00 = (1.f - dy) * (1.f - dx) * ((vy0 && vx0) ? 1.f : 0.f);
        float w01 = (1.f - dy) * dx         * ((vy0 && vx1) ? 1.f : 0.f);
        float w10 = dy * (1.f - dx)         * ((vy1 && vx0) ? 1.f : 0.f);
        float w11 = dy * dx                 * ((vy1 && vx1) ? 1.f : 0.f);

        const float* r00 = gbase + (size_t)(yc0 * WW + xc0) * CP;
        const float* r01 = gbase + (size_t)(yc0 * WW + xc1) * CP;
        const float* r10 = gbase + (size_t)(yc1 * WW + xc0) * CP;
        const float* r11 = gbase + (size_t)(yc1 * WW + xc1) * CP;

        float A00[18], A01[18], A10[18], A11[18];
        #pragma unroll
        for (int q = 0; q < 4; ++q) {
            *reinterpret_cast<float4*>(&A00[q * 4]) = *reinterpret_cast<const float4*>(r00 + q * 4);
            *reinterpret_cast<float4*>(&A01[q * 4]) = *reinterpret_cast<const float4*>(r01 + q * 4);
            *reinterpret_cast<float4*>(&A10[q * 4]) = *reinterpret_cast<const float4*>(r10 + q * 4);
            *reinterpret_cast<float4*>(&A11[q * 4]) = *reinterpret_cast<const float4*>(r11 + q * 4);
        }
        *reinterpret_cast<float2*>(&A00[16]) = *reinterpret_cast<const float2*>(r00 + 16);
        *reinterpret_cast<float2*>(&A01[16]) = *reinterpret_cast<const float2*>(r01 + 16);
        *reinterpret_cast<float2*>(&A10[16]) = *reinterpret_cast<const float2*>(r10 + 16);
        *reinterpret_cast<float2*>(&A11[16]) = *reinterpret_cast<const float2*>(r11 + 16);

        #pragma unroll
        for (int c = 0; c < 18; c += 2) {
            float v0 = w00 * A00[c]     + w01 * A01[c]     + w10 * A10[c]     + w11 * A11[c];
            float v1 = w00 * A00[c + 1] + w01 * A01[c + 1] + w10 * A10[c + 1] + w11 * A11[c + 1];
            u[kk * 9 + (c >> 1)] = (unsigned)f2bf(v0) | ((unsigned)f2bf(v1) << 16);
        }
    }

    unsigned* dst = patch2 + ((size_t)z * NDW + g * 88) * nchunk + pl;
    #pragma unroll
    for (int i = 0; i < 88; ++i)
        dst[(size_t)i * nchunk] = u[i];
}

// ---------------- MFMA bf16 dcn GEMM, both sets, LDS double-buffered ----------------
// grid (nchunk/64, 2 sets, NB). One barrier per K-step; global loads issued 2 steps
// ahead; ds_writes of tile kt+1 overlap MFMA of tile kt. LDS image per buffer is
// byte-identical to R12's verified layout.
__global__ __launch_bounds__(256)
void dgemm_k(const unsigned short* __restrict__ wbfA, const unsigned* __restrict__ patch2,
             const float* __restrict__ bW, const float* __restrict__ bH,
             float* __restrict__ fw, float* __restrict__ fh, int nchunk, int p0)
{
    __shared__ uint4 smem[2048];                 // 2 x (12KB A + 4KB B) = 32 KB
    char* lds = (char*)smem;
    const int set = blockIdx.y, b = blockIdx.z, n0 = blockIdx.x * 64;
    const int tid = threadIdx.x;
    const int wv = tid >> 6, l = tid & 63;
    const int lg = l >> 4, lm = l & 15;
    const int arow = tid >> 2, aseg = tid & 3;
    const int bdw = tid & 15, bpq = tid >> 4;

    const unsigned short* Ag = wbfA + (size_t)set * MP * KP + (size_t)arow * KP + aseg * 8;
    const unsigned* Bg = patch2 + (size_t)((b * 2 + set) * NDW) * nchunk + n0 + 4 * bpq;

    int wbA[3], wmA[3];
    #pragma unroll
    for (int i = 0; i < 3; ++i) {
        int row = arow + (i << 6);
        wbA[i] = row << 6;
        wmA[i] = (aseg << 4) ^ SWZ(row);
    }
    int wB[4];
    #pragma unroll
    for (int i = 0; i < 4; ++i) {
        int n = bpq * 4 + i;
        wB[i] = 12288 + (n << 6) + ((bdw << 2) ^ SWZ(n));
    }

    int aoff[3][2], boff[4][2];
    #pragma unroll
    for (int fr = 0; fr < 3; ++fr) {
        int row = wv * 48 + fr * 16 + lm;
        int m = SWZ(row);
        aoff[fr][0] = (row << 6) + (((lg << 3)     ) ^ m);
        aoff[fr][1] = (row << 6) + (((lg << 3) + 32) ^ m);
    }
    #pragma unroll
    for (int nc = 0; nc < 4; ++nc) {
        int n = nc * 16 + lm;
        int m = SWZ(n);
        boff[nc][0] = 12288 + (n << 6) + (((lg << 3)     ) ^ m);
        boff[nc][1] = 12288 + (n << 6) + (((lg << 3) + 32) ^ m);
    }

    f32x4 acc[3][4];
    #pragma unroll
    for (int i = 0; i < 3; ++i)
        #pragma unroll
        for (int j = 0; j < 4; ++j)
            acc[i][j] = (f32x4){0.f, 0.f, 0.f, 0.f};

    const int NT = KP / 32;   // 55

    // prologue: tile 0 -> regs -> buf0 ; tile 1 -> regs
    uint4 ra0 = *(const uint4*)(Ag);
    uint4 ra1 = *(const uint4*)(Ag + (size_t)64 * KP);
    uint4 ra2 = *(const uint4*)(Ag + (size_t)128 * KP);
    uint4 rb  = *(const uint4*)(Bg + (size_t)bdw * nchunk);
    {
        char* L = lds;
        *(uint2*)(L + wbA[0] + wmA[0])       = make_uint2(ra0.x, ra0.y);
        *(uint2*)(L + wbA[0] + (wmA[0] ^ 8)) = make_uint2(ra0.z, ra0.w);
        *(uint2*)(L + wbA[1] + wmA[1])       = make_uint2(ra1.x, ra1.y);
        *(uint2*)(L + wbA[1] + (wmA[1] ^ 8)) = make_uint2(ra1.z, ra1.w);
        *(uint2*)(L + wbA[2] + wmA[2])       = make_uint2(ra2.x, ra2.y);
        *(uint2*)(L + wbA[2] + (wmA[2] ^ 8)) = make_uint2(ra2.z, ra2.w);
        *(unsigned*)(L + wB[0]) = rb.x;
        *(unsigned*)(L + wB[1]) = rb.y;
        *(unsigned*)(L + wB[2]) = rb.z;
        *(unsigned*)(L + wB[3]) = rb.w;
    }
    ra0 = *(const uint4*)(Ag + 32);
    ra1 = *(const uint4*)(Ag + (size_t)64 * KP + 32);
    ra2 = *(const uint4*)(Ag + (size_t)128 * KP + 32);
    rb  = *(const uint4*)(Bg + (size_t)(16 + bdw) * nchunk);
    __syncthreads();

    int cb = 0;
    for (int kt = 0; kt < NT; ++kt) {
        const int nb = cb ^ 16384;
        if (kt + 1 < NT) {
            char* L = lds + nb;
            *(uint2*)(L + wbA[0] + wmA[0])       = make_uint2(ra0.x, ra0.y);
            *(uint2*)(L + wbA[0] + (wmA[0] ^ 8)) = make_uint2(ra0.z, ra0.w);
            *(uint2*)(L + wbA[1] + wmA[1])       = make_uint2(ra1.x, ra1.y);
            *(uint2*)(L + wbA[1] + (wmA[1] ^ 8)) = make_uint2(ra1.z, ra1.w);
            *(uint2*)(L + wbA[2] + wmA[2])       = make_uint2(ra2.x, ra2.y);
            *(uint2*)(L + wbA[2] + (wmA[2] ^ 8)) = make_uint2(ra2.z, ra2.w);
            *(unsigned*)(L + wB[0]) = rb.x;
            *(unsigned*)(L + wB[1]) = rb.y;
            *(unsigned*)(L + wB[2]) = rb.z;
            *(unsigned*)(L + wB[3]) = rb.w;
            if (kt + 2 < NT) {
                const int k0 = (kt + 2) * 32;
                ra0 = *(const uint4*)(Ag + k0);
                ra1 = *(const uint4*)(Ag + (size_t)64 * KP + k0);
                ra2 = *(const uint4*)(Ag + (size_t)128 * KP + k0);
                rb  = *(const uint4*)(Bg + (size_t)((kt + 2) * 16 + bdw) * nchunk);
            }
        }
        char* Lc = lds + cb;
        FragU af[3], bf[4];
        #pragma unroll
        for (int fr = 0; fr < 3; ++fr) {
            af[fr].u2[0] = *(const uint2*)(Lc + aoff[fr][0]);
            af[fr].u2[1] = *(const uint2*)(Lc + aoff[fr][1]);
        }
        #pragma unroll
        for (int nc = 0; nc < 4; ++nc) {
            bf[nc].u2[0] = *(const uint2*)(Lc + boff[nc][0]);
            bf[nc].u2[1] = *(const uint2*)(Lc + boff[nc][1]);
        }
        #pragma unroll
        for (int fr = 0; fr < 3; ++fr)
            #pragma unroll
            for (int nc = 0; nc < 4; ++nc)
                acc[fr][nc] = __builtin_amdgcn_mfma_f32_16x16x32_bf16(
                    af[fr].v, bf[nc].v, acc[fr][nc], 0, 0, 0);
        __syncthreads();
        cb = nb;
    }

    const float* bias = set ? bH : bW;
    float* fD = set ? fh : fw;
    #pragma unroll
    for (int fr = 0; fr < 3; ++fr) {
        #pragma unroll
        for (int r = 0; r < 4; ++r) {
            int rr = wv * 48 + fr * 16 + lg * 4 + r;
            if (rr < CMID) {
                float bi = bias[rr];
                float* Cr = fD + (size_t)b * CMID * HW + (size_t)rr * HW + p0 + n0 + lm;
                #pragma unroll
                for (int nc = 0; nc < 4; ++nc)
                    Cr[nc * 16] = acc[fr][nc][r] + bi;
            }
        }
    }
}

// ---------------- mean over HW of (f_w + f_h) ----------------
__global__ __launch_bounds__(256)
void avg_k(const float* __restrict__ fw, const float* __restrict__ fh,
           float* __restrict__ favg)
{
    const int bm = blockIdx.x;
    const size_t base = (size_t)bm * HW;
    float s = 0.f;
    for (int i = threadIdx.x; i < HW; i += 256)
        s += fw[base + i] + fh[base + i];
    #pragma unroll
    for (int off = 32; off > 0; off >>= 1) s += __shfl_down(s, off, 64);
    __shared__ float sb[4];
    const int tid = threadIdx.x;
    if ((tid & 63) == 0) sb[tid >> 6] = s;
    __syncthreads();
    if (tid == 0) favg[bm] = (sb[0] + sb[1] + sb[2] + sb[3]) / (float)HW;
}

// ---------------- attention softmax ----------------
__global__ __launch_bounds__(256)
void attn_k(const float* __restrict__ favg, const float* __restrict__ w_attn,
            const float* __restrict__ b_attn, float* __restrict__ attnb)
{
    const int b = blockIdx.x;
    const int t = threadIdx.x;
    float z0 = 0.f, z1 = 0.f;
    if (t < CMID) {
        float f = favg[b * CMID + t];
        z0 = w_attn[t] * f;
        z1 = w_attn[CMID + t] * f;
    }
    #pragma unroll
    for (int off = 32; off > 0; off >>= 1) {
        z0 += __shfl_down(z0, off, 64);
        z1 += __shfl_down(z1, off, 64);
    }
    __shared__ float s0[4], s1[4];
    if ((t & 63) == 0) { s0[t >> 6] = z0; s1[t >> 6] = z1; }
    __syncthreads();
    if (t == 0) {
        float a = s0[0] + s0[1] + s0[2] + s0[3] + b_attn[0];
        float c = s1[0] + s1[1] + s1[2] + s1[3] + b_attn[1];
        float m = fmaxf(a, c);
        float e0 = expf(a - m), e1 = expf(c - m);
        float inv = 1.f / (e0 + e1);
        attnb[2 * b + 0] = e0 * inv;   // multiplies f_h
        attnb[2 * b + 1] = e1 * inv;   // multiplies f_w
    }
}

extern "C" void kernel_launch(void* const* d_in, const int* in_sizes, int n_in,
                              void* d_out, int out_size, void* d_ws, size_t ws_size,
                              hipStream_t stream) {
    const float* x        = (const float*)d_in[0];
    const float* w_reduce = (const float*)d_in[1];
    const float* b_reduce = (const float*)d_in[2];
    const float* w_offset = (const float*)d_in[3];
    const float* b_offset = (const float*)d_in[4];
    const float* w_dcnw   = (const float*)d_in[5];
    const float* b_dcnw   = (const float*)d_in[6];
    const float* w_dcnh   = (const float*)d_in[7];
    const float* b_dcnh   = (const float*)d_in[8];
    const float* w_expand = (const float*)d_in[9];
    const float* b_expand = (const float*)d_in[10];
    const float* w_attn   = (const float*)d_in[11];
    const float* b_attn   = (const float*)d_in[12];
    float* out = (float*)d_out;

    // workspace layout
    char* base = (char*)d_ws;
    size_t o = 0;
    float* xr    = (float*)(base + o); o += (size_t)NB * CMID * HW * 4;
    float* offs  = (float*)(base + o); o += (size_t)NB * 2 * CMID * HW * 4;
    float* fw    = (float*)(base + o); o += (size_t)NB * CMID * HW * 4;
    float* fh    = (float*)(base + o); o += (size_t)NB * CMID * HW * 4;
    float* favg  = (float*)(base + o); o += (size_t)NB * CMID * 4;
    float* attnb = (float*)(base + o); o += 32;
    float* xrt   = (float*)(base + o); o += (size_t)NB * NG * HW * CP * 4;   // 14.75 MB
    unsigned short* wbf = (unsigned short*)(base + o); o += (size_t)2 * MP * KP * 2;
    unsigned* patch2 = (unsigned*)(base + o);

    // choose chunk so BOTH sets' patch regions fit: NB*2 * nchunk * KP * 2 bytes
    int nchunk = 2304;
    const int cand[3] = {9216, 4608, 2304};        // all divisible by 256
    for (int i = 0; i < 3; ++i) {
        size_t need = o + (size_t)NB * 2 * cand[i] * KP * 2;
        if (need <= ws_size) { nchunk = cand[i]; break; }
    }

    // 0) convert dcn weights to tap-major padded bf16 layout
    convw5_k<<<dim3((2 * MP * KP) / 256), 256, 0, stream>>>(w_dcnw, w_dcnh, wbf);

    // 1) xr = w_reduce @ x + b_reduce  (+ channel-last xrt scatter)
    gemm_k<false, true><<<dim3(3, HW / 64, NB), 256, 0, stream>>>(
        w_reduce, x, nullptr, nullptr, b_reduce, xr, xrt,
        CMID, HW, CIN, HW, HW, CIN * HW, CMID * HW);

    // 2) offs = w_offset @ xr + b_offset
    gemm_k<false, false><<<dim3(6, HW / 64, NB), 256, 0, stream>>>(
        w_offset, xr, nullptr, nullptr, b_offset, offs, nullptr,
        2 * CMID, HW, CMID, HW, HW, CMID * HW, 2 * CMID * HW);

    // 3) deformable convs via bf16 MFMA — both sets per dispatch
    for (int p0 = 0; p0 < HW; p0 += nchunk) {
        gather6_k<<<dim3(nchunk / 256, NG, NB * 2), 256, 0, stream>>>(
            xrt, offs, patch2, p0, nchunk);
        dgemm_k<<<dim3(nchunk / 64, 2, NB), 256, 0, stream>>>(
            wbf, patch2, b_dcnw, b_dcnh, fw, fh, nchunk, p0);
    }

    // 4) f_avg = mean_HW(f_w + f_h)
    avg_k<<<dim3(NB * CMID), 256, 0, stream>>>(fw, fh, favg);

    // 5) attn = softmax(w_attn @ f_avg + b_attn)
    attn_k<<<dim3(NB), 256, 0, stream>>>(favg, w_attn, b_attn, attnb);

    // 6) out = w_expand @ (a0*f_h + a1*f_w) + b_expand
    gemm_k<true, false><<<dim3(3, HW / 64, NB), 256, 0, stream>>>(
        w_expand, fh, fw, attnb, b_expand, out, nullptr,
        CIN, HW, CMID, HW, HW, CMID * HW, CIN * HW);
}